// Round 9
// baseline (174.813 us; speedup 1.0000x reference)
//
#include <hip/hip_runtime.h>

typedef int v4i __attribute__((ext_vector_type(4)));

#define NIMG 32
#define CIN  256
#define COUT 256
#define HW   3136   // 56*56
#define W56  56
#define HP   58     // padded H/W
#define PIMG (HP * HP)                       // 3364
#define XQP_BYTES (NIMG * PIMG * CIN)        // 27,557,888
#define WP_BYTES  (9 * COUT * CIN)           // 589,824

#define BARRIER() asm volatile("s_barrier" ::: "memory")
#define VMCNT0()  asm volatile("s_waitcnt vmcnt(0)" ::: "memory")

// ---------------------------------------------------------------------------
// Kernel 0: zero only the pad border (228 px/image * 256B)
// ---------------------------------------------------------------------------
__global__ __launch_bounds__(256) void zero_border(v4i* __restrict__ p)
{
    int i = blockIdx.x * 256 + threadIdx.x;
    if (i >= NIMG * 228 * 16) return;
    int n = i / 3648, r = i % 3648, pix = r >> 4, c = r & 15;
    int h, w;
    if (pix < 58)       { h = 0;         w = pix;       }
    else if (pix < 116) { h = 57;        w = pix - 58;  }
    else if (pix < 172) { h = pix - 115; w = 0;         }
    else                { h = pix - 171; w = 57;        }
    v4i z = {0, 0, 0, 0};
    p[(size_t)(n * PIMG + h * HP + w) * 16 + c] = z;
}

// ---------------------------------------------------------------------------
// Kernel 1: quantize + transpose  NCHW f32 -> padded NHWC int8 (interior)
// ---------------------------------------------------------------------------
__global__ __launch_bounds__(256) void quantize_pad(
    const float* __restrict__ x, signed char* __restrict__ xqp)
{
    __shared__ int tile[64][65];
    const int n  = blockIdx.z;
    const int c0 = blockIdx.y * 64;
    const int p0 = blockIdx.x * 64;
    const int tid = threadIdx.x;

    const int px   = tid & 63;
    const int crow = tid >> 6;
    const float* xb = x + ((size_t)(n * CIN + c0)) * HW + p0;
#pragma unroll
    for (int i = 0; i < 16; ++i) {
        int c = crow + i * 4;
        float v = xb[(size_t)c * HW + px];
        v = fminf(fmaxf(v, -1.f), 1.f);
        tile[c][px] = (int)rintf(v * 127.f);
    }
    __syncthreads();

    const int c4   = tid & 15;
    const int prow = tid >> 4;
#pragma unroll
    for (int i = 0; i < 4; ++i) {
        int p  = prow + i * 16;
        int hw = p0 + p;
        int oh = hw / W56, ow = hw % W56;
        int b0 = tile[c4 * 4 + 0][p] & 255;
        int b1 = tile[c4 * 4 + 1][p] & 255;
        int b2 = tile[c4 * 4 + 2][p] & 255;
        int b3 = tile[c4 * 4 + 3][p] & 255;
        int packed = b0 | (b1 << 8) | (b2 << 16) | (b3 << 24);
        *(int*)(xqp + ((size_t)(n * PIMG + (oh + 1) * HP + (ow + 1))) * CIN
                    + c0 + c4 * 4) = packed;
    }
}

// ---------------------------------------------------------------------------
// Kernel 2: weight repack  OIHW int32{-1,0,1} -> [step 0..35][cout 256][64B]
// ---------------------------------------------------------------------------
__global__ __launch_bounds__(256) void repack_w(
    const int* __restrict__ wq, signed char* __restrict__ wp2)
{
    int idx  = blockIdx.x * 256 + threadIdx.x;   // < 589824
    int t    = idx >> 16;
    int rem  = idx & 65535;
    int kc   = rem >> 14;
    int rem2 = rem & 16383;
    int co   = rem2 >> 6;
    int c6   = rem2 & 63;
    int ci   = kc * 64 + c6;
    wp2[idx] = (signed char)wq[(co * CIN + ci) * 9 + t];
}

// ---------------------------------------------------------------------------
// Kernel 3: implicit-GEMM conv.
// A (weights, L2-resident) via 3-ring LDS (24KB) + prefetched ds_reads.
// B (activations) DIRECT global->VGPR, 1-step register prefetch (async VMEM
// overlaps MFMA within the step; no B LDS traffic, no lgkm before MFMA).
// Block 128 cout x 128 px, 4 waves (2x2) of 64x64, one barrier per step.
// ---------------------------------------------------------------------------
__device__ __forceinline__ void gll16(const void* g, void* l)
{
    __builtin_amdgcn_global_load_lds(
        (const __attribute__((address_space(1))) int*)g,
        (__attribute__((address_space(3))) int*)l, 16, 0, 0);
}

__device__ __forceinline__ int boffset(int s)
{
    int t9 = s >> 2, kc = s & 3;
    return ((t9 / 3 - 1) * HP + (t9 % 3 - 1)) * CIN + kc * 64;
}

__global__ __launch_bounds__(256) void bitconv_mfma(
    const signed char* __restrict__ xqp, const signed char* __restrict__ wp2,
    const float* __restrict__ s_, const float* __restrict__ bias,
    const float* __restrict__ act_s_p, float* __restrict__ out)
{
    __shared__ signed char As[3][8192];   // 3-ring, 128 cout x 64B each

    const int tid  = threadIdx.x;
    const int lane = tid & 63;
    const int wid  = tid >> 6;          // 0..3
    const int wr   = wid >> 1;          // cout half
    const int wc   = wid & 1;           // px half
    const int l15  = lane & 15;
    const int kg   = lane >> 4;
    const int kgs  = ((kg ^ ((l15 >> 1) & 3)) << 4);   // swizzled A chunk

    // XCD-bijective swizzle (1568 % 8 == 0)
    const int b  = blockIdx.x;
    const int w  = (b & 7) * 196 + (b >> 3);
    const int px0   = (w >> 1) * 128;
    const int cout0 = (w & 1) * 128;

    // ---- A staging source (swizzle baked into global src; LDS dest linear)
    const int srow   = tid >> 2;                         // 0..63
    const int schunk = (((tid & 3) ^ ((tid >> 3) & 3)) << 4);
    const signed char* asrc = wp2 + cout0 * 64 + srow * 64 + schunk;

    // ---- B per-lane fragment base pointers (16 pixels per fragment) ----
    const signed char* bp[4];
#pragma unroll
    for (int j = 0; j < 4; ++j) {
        int p = px0 + wc * 64 + j * 16 + l15;
        int n = p / HW, q = p % HW;
        bp[j] = xqp
            + ((size_t)(n * PIMG + (q / W56 + 1) * HP + (q % W56 + 1))) * CIN
            + kg * 16;
    }

    // ---- A fragment ds_read offsets (swizzled) ----
    int aoff[4];
#pragma unroll
    for (int i = 0; i < 4; ++i)
        aoff[i] = (wr * 64 + i * 16 + l15) * 64 + kgs;

    v4i acc[4][4] = {};
    v4i areg[2][4], breg[2][4];

    const int wb = wid * 1024;          // wave-uniform LDS sub-base

    auto stageA = [&](int buf, int s) { // 2 gll16: A 8KB (128 rows)
        signed char* L = &As[buf][0];
        const signed char* a = asrc + s * 16384;
        gll16(a,        L + wb);
        gll16(a + 4096, L + 4096 + wb);
    };

    // ---- prologue: B(0) regs, A(0),A(1) staged; drain; first a-frags ----
    {
        int off0 = boffset(0);
#pragma unroll
        for (int j = 0; j < 4; ++j)
            breg[0][j] = *(const v4i*)(bp[j] + off0);
    }
    stageA(0, 0);
    stageA(1, 1);
    VMCNT0();
    BARRIER();
#pragma unroll
    for (int i = 0; i < 4; ++i)
        areg[0][i] = *(const v4i*)(&As[0][0] + aoff[i]);

    for (int it = 0; it < 6; ++it) {
#pragma unroll
        for (int u = 0; u < 6; ++u) {
            const int s   = it * 6 + u;
            const int cu  = u & 1;          // static
            const int nx  = cu ^ 1;         // static
            const int nbf = (u + 1) % 3;    // static: (s+1)%3

            // issue B(s+1) -> regs (async VMEM, overlaps MFMA below)
            if (s < 35) {
                int off = boffset(s + 1);
#pragma unroll
                for (int j = 0; j < 4; ++j)
                    breg[nx][j] = *(const v4i*)(bp[j] + off);
            }
            // stage A(s+2) (ring buf (s+2)%3; readers of it finished at s-1)
            if (s < 34) stageA((u + 2) % 3, s + 2);

            // prefetch a(s+1) from buf (s+1)%3 (staged at s-1, drained then)
            if (s < 35) {
#pragma unroll
                for (int i = 0; i < 4; ++i)
                    areg[nx][i] = *(const v4i*)(&As[nbf][0] + aoff[i]);
            }

            __builtin_amdgcn_s_setprio(1);
#pragma unroll
            for (int i = 0; i < 4; ++i)
#pragma unroll
                for (int j = 0; j < 4; ++j)
                    acc[i][j] = __builtin_amdgcn_mfma_i32_16x16x64_i8(
                        areg[cu][i], breg[cu][j], acc[i][j], 0, 0, 0);
            __builtin_amdgcn_s_setprio(0);

            if (s < 35) {
                VMCNT0();     // B(s+1) regs + A(s+2) LDS writes complete
                BARRIER();    // A-ring WAR/visibility across waves
            }
        }
    }

    // ---- epilogue: y = acc * (act_s * s[c]) + bias[c], NCHW f32 ----
    const float a_s = act_s_p[0];
    int nn[4], hh[4];
#pragma unroll
    for (int j = 0; j < 4; ++j) {
        int op = px0 + wc * 64 + j * 16 + l15;
        nn[j] = op / HW;
        hh[j] = op % HW;
    }
#pragma unroll
    for (int i = 0; i < 4; ++i) {
        int cb = cout0 + wr * 64 + i * 16 + kg * 4;
        float sc[4], bi[4];
#pragma unroll
        for (int r = 0; r < 4; ++r) {
            sc[r] = a_s * s_[cb + r];
            bi[r] = bias[cb + r];
        }
#pragma unroll
        for (int j = 0; j < 4; ++j)
#pragma unroll
            for (int r = 0; r < 4; ++r)
                out[((size_t)(nn[j] * COUT + cb + r)) * HW + hh[j]] =
                    (float)acc[i][j][r] * sc[r] + bi[r];
    }
}

// ---------------------------------------------------------------------------
extern "C" void kernel_launch(void* const* d_in, const int* in_sizes, int n_in,
                              void* d_out, int out_size, void* d_ws, size_t ws_size,
                              hipStream_t stream)
{
    const float* x     = (const float*)d_in[0];
    const int*   w_q   = (const int*)d_in[1];
    const float* s     = (const float*)d_in[2];
    const float* bias  = (const float*)d_in[3];
    const float* act_s = (const float*)d_in[4];

    signed char* xqp = (signed char*)d_ws;
    signed char* wp2 = (signed char*)d_ws + XQP_BYTES;

    zero_border<<<(NIMG * 228 * 16 + 255) / 256, 256, 0, stream>>>((v4i*)xqp);
    quantize_pad<<<dim3(49, 4, NIMG), 256, 0, stream>>>(x, xqp);
    repack_w<<<dim3(WP_BYTES / 256), 256, 0, stream>>>(w_q, wp2);
    bitconv_mfma<<<dim3(1568), 256, 0, stream>>>(
        xqp, wp2, s, bias, act_s, (float*)d_out);
}

// Round 10
// 99.294 us; speedup vs baseline: 1.7606x; 1.7606x over previous
//
#include <hip/hip_runtime.h>

typedef int v4i __attribute__((ext_vector_type(4)));

#define NIMG 32
#define CIN  256
#define COUT 256
#define HW   3136   // 56*56
#define W56  56
#define HP   58     // padded H/W
#define PIMG (HP * HP)                       // 3364
#define XQP_BYTES (NIMG * PIMG * CIN)        // 27,557,888
#define WP_BYTES  (9 * COUT * CIN)           // 589,824

#define BARRIER() asm volatile("s_barrier" ::: "memory")
#define VMCNT0()  asm volatile("s_waitcnt vmcnt(0)" ::: "memory")

// ---------------------------------------------------------------------------
// Kernel 0: zero only the pad border (228 px/image * 256B)
// ---------------------------------------------------------------------------
__global__ __launch_bounds__(256) void zero_border(v4i* __restrict__ p)
{
    int i = blockIdx.x * 256 + threadIdx.x;
    if (i >= NIMG * 228 * 16) return;
    int n = i / 3648, r = i % 3648, pix = r >> 4, c = r & 15;
    int h, w;
    if (pix < 58)       { h = 0;         w = pix;       }
    else if (pix < 116) { h = 57;        w = pix - 58;  }
    else if (pix < 172) { h = pix - 115; w = 0;         }
    else                { h = pix - 171; w = 57;        }
    v4i z = {0, 0, 0, 0};
    p[(size_t)(n * PIMG + h * HP + w) * 16 + c] = z;
}

// ---------------------------------------------------------------------------
// Kernel 1: quantize + transpose  NCHW f32 -> padded NHWC int8 (interior)
// ---------------------------------------------------------------------------
__global__ __launch_bounds__(256) void quantize_pad(
    const float* __restrict__ x, signed char* __restrict__ xqp)
{
    __shared__ int tile[64][65];
    const int n  = blockIdx.z;
    const int c0 = blockIdx.y * 64;
    const int p0 = blockIdx.x * 64;
    const int tid = threadIdx.x;

    const int px   = tid & 63;
    const int crow = tid >> 6;
    const float* xb = x + ((size_t)(n * CIN + c0)) * HW + p0;
#pragma unroll
    for (int i = 0; i < 16; ++i) {
        int c = crow + i * 4;
        float v = xb[(size_t)c * HW + px];
        v = fminf(fmaxf(v, -1.f), 1.f);
        tile[c][px] = (int)rintf(v * 127.f);
    }
    __syncthreads();

    const int c4   = tid & 15;
    const int prow = tid >> 4;
#pragma unroll
    for (int i = 0; i < 4; ++i) {
        int p  = prow + i * 16;
        int hw = p0 + p;
        int oh = hw / W56, ow = hw % W56;
        int b0 = tile[c4 * 4 + 0][p] & 255;
        int b1 = tile[c4 * 4 + 1][p] & 255;
        int b2 = tile[c4 * 4 + 2][p] & 255;
        int b3 = tile[c4 * 4 + 3][p] & 255;
        int packed = b0 | (b1 << 8) | (b2 << 16) | (b3 << 24);
        *(int*)(xqp + ((size_t)(n * PIMG + (oh + 1) * HP + (ow + 1))) * CIN
                    + c0 + c4 * 4) = packed;
    }
}

// ---------------------------------------------------------------------------
// Kernel 2: weight repack  OIHW int32{-1,0,1} -> [sub 0..35][cout 256][64B]
// ---------------------------------------------------------------------------
__global__ __launch_bounds__(256) void repack_w(
    const int* __restrict__ wq, signed char* __restrict__ wp2)
{
    int idx  = blockIdx.x * 256 + threadIdx.x;   // < 589824
    int t    = idx >> 16;
    int rem  = idx & 65535;
    int kc   = rem >> 14;
    int rem2 = rem & 16383;
    int co   = rem2 >> 6;
    int c6   = rem2 & 63;
    int ci   = kc * 64 + c6;
    wp2[idx] = (signed char)wq[(co * CIN + ci) * 9 + t];
}

// ---------------------------------------------------------------------------
// Kernel 3: implicit-GEMM conv, BK=128 (two fused 64-substeps), ONE barrier
// + ONE vmcnt per step (18 steps vs 36). Tile 128x128, 4 waves of 64x64,
// 2-deep double buffer (2x32KB, 2 blocks/CU), R5-proven swizzle/addressing.
// ---------------------------------------------------------------------------
__device__ __forceinline__ void gll16(const void* g, void* l)
{
    __builtin_amdgcn_global_load_lds(
        (const __attribute__((address_space(1))) int*)g,
        (__attribute__((address_space(3))) int*)l, 16, 0, 0);
}

__device__ __forceinline__ int boffset(int ss)   // substep 0..35
{
    int t9 = ss >> 2, kc = ss & 3;
    return ((t9 / 3 - 1) * HP + (t9 % 3 - 1)) * CIN + kc * 64;
}

__global__ __launch_bounds__(256) void bitconv_mfma(
    const signed char* __restrict__ xqp, const signed char* __restrict__ wp2,
    const float* __restrict__ s_, const float* __restrict__ bias,
    const float* __restrict__ act_s_p, float* __restrict__ out)
{
    // buffer layout: sub0 {A 8K | B 8K} at 0, sub1 {A 8K | B 8K} at 16K
    __shared__ signed char lds[2][32768];

    const int tid  = threadIdx.x;
    const int lane = tid & 63;
    const int wid  = tid >> 6;          // 0..3
    const int wr   = wid >> 1;          // cout half
    const int wc   = wid & 1;           // px half
    const int l15  = lane & 15;
    const int kg   = lane >> 4;
    const int kgs  = ((kg ^ ((l15 >> 1) & 3)) << 4);   // swizzled chunk

    // XCD-bijective swizzle (1568 % 8 == 0)
    const int b  = blockIdx.x;
    const int w  = (b & 7) * 196 + (b >> 3);
    const int px0   = (w >> 1) * 128;
    const int cout0 = (w & 1) * 128;

    // ---- staging addresses (swizzle baked into the global source) ----
    const int srow   = tid >> 2;                         // 0..63
    const int schunk = (((tid & 3) ^ ((tid >> 3) & 3)) << 4);
    const signed char* asrc = wp2 + cout0 * 64 + srow * 64 + schunk;

    const signed char* bsrc[2];
#pragma unroll
    for (int r = 0; r < 2; ++r) {
        int p = px0 + srow + r * 64;
        int n = p / HW, q = p % HW;
        bsrc[r] = xqp
            + ((size_t)(n * PIMG + (q / W56 + 1) * HP + (q % W56 + 1))) * CIN
            + schunk;
    }

    // ---- fragment ds_read offsets (swizzled) ----
    int aoff[4], boff[4];
#pragma unroll
    for (int i = 0; i < 4; ++i)
        aoff[i] = (wr * 64 + i * 16 + l15) * 64 + kgs;
#pragma unroll
    for (int j = 0; j < 4; ++j)
        boff[j] = 8192 + (wc * 64 + j * 16 + l15) * 64 + kgs;

    v4i acc[4][4] = {};

    const int wb = wid * 1024;          // wave-uniform LDS sub-base

    // stage substeps 2t and 2t+1 into lds[buf] (8 gll16, 32KB)
    auto stage = [&](int buf, int t) {
        signed char* L = &lds[buf][0];
#pragma unroll
        for (int h = 0; h < 2; ++h) {
            const int ss = 2 * t + h;
            const signed char* a = asrc + ss * 16384;
            const int R = h * 16384;
            gll16(a,        L + R + wb);
            gll16(a + 4096, L + R + 4096 + wb);
            int bo = boffset(ss);
            gll16(bsrc[0] + bo, L + R + 8192  + wb);
            gll16(bsrc[1] + bo, L + R + 12288 + wb);
        }
    };

    // prologue: step 0 staged and drained
    stage(0, 0);
    VMCNT0();
    BARRIER();

    for (int it = 0; it < 9; ++it) {
#pragma unroll
        for (int u = 0; u < 2; ++u) {
            const int t = it * 2 + u;       // step 0..17
            const signed char* L = &lds[u][0];

            if (t < 17) stage(u ^ 1, t + 1);   // issue-early; drained at end

            // ---- sub0 ----
            v4i a[4], bb[4];
#pragma unroll
            for (int i = 0; i < 4; ++i) a[i]  = *(const v4i*)(L + aoff[i]);
#pragma unroll
            for (int j = 0; j < 4; ++j) bb[j] = *(const v4i*)(L + boff[j]);

            __builtin_amdgcn_s_setprio(1);
#pragma unroll
            for (int i = 0; i < 4; ++i)
#pragma unroll
                for (int j = 0; j < 4; ++j)
                    acc[i][j] = __builtin_amdgcn_mfma_i32_16x16x64_i8(
                        a[i], bb[j], acc[i][j], 0, 0, 0);
            __builtin_amdgcn_s_setprio(0);

            // ---- sub1 (reads hoist under sub0's MFMAs via compiler lgkm) ----
            v4i a2[4], bb2[4];
#pragma unroll
            for (int i = 0; i < 4; ++i) a2[i]  = *(const v4i*)(L + 16384 + aoff[i]);
#pragma unroll
            for (int j = 0; j < 4; ++j) bb2[j] = *(const v4i*)(L + 16384 + boff[j]);

            __builtin_amdgcn_s_setprio(1);
#pragma unroll
            for (int i = 0; i < 4; ++i)
#pragma unroll
                for (int j = 0; j < 4; ++j)
                    acc[i][j] = __builtin_amdgcn_mfma_i32_16x16x64_i8(
                        a2[i], bb2[j], acc[i][j], 0, 0, 0);
            __builtin_amdgcn_s_setprio(0);

            if (t < 17) {
                VMCNT0();    // next buffer's 8 loads complete (issued ~1700cy ago)
                BARRIER();   // WAR: everyone done reading buf u before reuse
            }
        }
    }

    // ---- epilogue: y = acc * (act_s * s[c]) + bias[c], NCHW f32 ----
    const float a_s = act_s_p[0];
    int nn[4], hh[4];
#pragma unroll
    for (int j = 0; j < 4; ++j) {
        int op = px0 + wc * 64 + j * 16 + l15;
        nn[j] = op / HW;
        hh[j] = op % HW;
    }
#pragma unroll
    for (int i = 0; i < 4; ++i) {
        int cb = cout0 + wr * 64 + i * 16 + kg * 4;
        float sc[4], bi[4];
#pragma unroll
        for (int r = 0; r < 4; ++r) {
            sc[r] = a_s * s_[cb + r];
            bi[r] = bias[cb + r];
        }
#pragma unroll
        for (int j = 0; j < 4; ++j)
#pragma unroll
            for (int r = 0; r < 4; ++r)
                out[((size_t)(nn[j] * COUT + cb + r)) * HW + hh[j]] =
                    (float)acc[i][j][r] * sc[r] + bi[r];
    }
}

// ---------------------------------------------------------------------------
extern "C" void kernel_launch(void* const* d_in, const int* in_sizes, int n_in,
                              void* d_out, int out_size, void* d_ws, size_t ws_size,
                              hipStream_t stream)
{
    const float* x     = (const float*)d_in[0];
    const int*   w_q   = (const int*)d_in[1];
    const float* s     = (const float*)d_in[2];
    const float* bias  = (const float*)d_in[3];
    const float* act_s = (const float*)d_in[4];

    signed char* xqp = (signed char*)d_ws;
    signed char* wp2 = (signed char*)d_ws + XQP_BYTES;

    zero_border<<<(NIMG * 228 * 16 + 255) / 256, 256, 0, stream>>>((v4i*)xqp);
    quantize_pad<<<dim3(49, 4, NIMG), 256, 0, stream>>>(x, xqp);
    repack_w<<<dim3(WP_BYTES / 256), 256, 0, stream>>>(w_q, wp2);
    bitconv_mfma<<<dim3(1568), 256, 0, stream>>>(
        xqp, wp2, s, bias, act_s, (float*)d_out);
}